// Round 1
// baseline (338.645 us; speedup 1.0000x reference)
//
#include <hip/hip_runtime.h>

// Sizes (fixed by the problem)
#define S_IN 256
#define S_D1 128
#define S_D2 64
#define IN_PER_BATCH (S_IN * S_IN * S_IN)          // 16,777,216
#define D1_PER_BATCH (S_D1 * S_D1 * S_D1)          // 2,097,152
#define D2_PER_BATCH (S_D2 * S_D2 * S_D2)          // 262,144
#define X_ELEMS (2 * IN_PER_BATCH)
#define D1_ELEMS (2 * D1_PER_BATCH)
#define D2_ELEMS (2 * D2_PER_BATCH)

// Input tile per block (must be multiples of 4 for d2 alignment)
#define TD 8
#define TH 8
#define TW 64
#define LZ (TD + 4)          // 12 (halo 2 each side)
#define LY (TH + 4)          // 12
#define LX (TW + 8)          // 72 floats: staged x range [x0-4, x0+67], 16B aligned
#define LDS_ELEMS (LZ * LY * LX)   // 10368 floats = 40.5 KB

__global__ __launch_bounds__(256) void fused_pyramid(
    const float* __restrict__ x, const float* __restrict__ k0,
    const float* __restrict__ k1, float* __restrict__ out0,
    float* __restrict__ out1, float* __restrict__ out2)
{
    __shared__ float ls[LDS_ELEMS];
    __shared__ float kw0[27];
    __shared__ float kw1[125];

    const int tid = threadIdx.x;
    if (tid < 27) kw0[tid] = k0[tid];
    else if (tid >= 32 && tid < 32 + 125) kw1[tid - 32] = k1[tid - 32];

    const int bx = blockIdx.x;
    const int wt = bx & 3;           // 4 W-tiles
    const int hy = (bx >> 2) & 31;   // 32 H-tiles
    const int dz = (bx >> 7) & 31;   // 32 D-tiles
    const int n  = bx >> 12;         // 2 batches

    const int x0 = wt * TW;
    const int y0 = hy * TH;
    const int z0 = dz * TD;

    const float* xb = x + (size_t)n * IN_PER_BATCH;

    // ---- Stage input tile (+halo) into LDS, aligned float4 loads ----
    // 144 rows (12 z x 12 y), 18 float4 per row starting at gx = x0 - 4.
    for (int v = tid; v < 144 * 18; v += 256) {
        int row = v / 18;
        int j   = v - row * 18;
        int lz  = row / LY;
        int ly  = row - lz * LY;
        int gz = z0 + lz - 2; gz = gz < 0 ? 0 : (gz > S_IN - 1 ? S_IN - 1 : gz);
        int gy = y0 + ly - 2; gy = gy < 0 ? 0 : (gy > S_IN - 1 ? S_IN - 1 : gy);
        const float* rp = xb + ((size_t)gz * S_IN + gy) * S_IN;
        int gx = x0 - 4 + 4 * j;
        float4 val;
        if (gx >= 0 && gx <= S_IN - 4) {
            val = *reinterpret_cast<const float4*>(rp + gx);
        } else {
            // whole vector is out of range on one side -> replicate-edge splat
            float s = rp[gx < 0 ? 0 : (S_IN - 1)];
            val = make_float4(s, s, s, s);
        }
        *reinterpret_cast<float4*>(&ls[(lz * LY + ly) * LX + 4 * j]) = val;
    }
    __syncthreads();

    // ---- 1) passthrough copy of the core 8x8x64 region (float4) ----
    {
        float* ob0 = out0 + (size_t)n * IN_PER_BATCH;
#pragma unroll
        for (int i = 0; i < 4; ++i) {
            int v   = tid + 256 * i;     // 0..1023 float4s
            int row = v >> 4;            // 0..63  (8 z x 8 y)
            int j   = v & 15;            // 16 float4 per row
            int lz  = row >> 3;          // 0..7
            int ly  = row & 7;           // 0..7
            float4 val = *reinterpret_cast<const float4*>(
                &ls[((lz + 2) * LY + (ly + 2)) * LX + 4 + 4 * j]);
            int gz = z0 + lz, gy = y0 + ly, gxo = x0 + 4 * j;
            *reinterpret_cast<float4*>(
                &ob0[((size_t)gz * S_IN + gy) * S_IN + gxo]) = val;
        }
    }

    // ---- 2) d1: 3x3x3 blur stride 2 -> 4x4x32 outputs, 2 per thread ----
    {
        float* ob1 = out1 + (size_t)n * D1_PER_BATCH;
        const int ox  = tid & 31;
        const int oy  = (tid >> 5) & 3;
        const int ozb = tid >> 7;        // 0..1
#pragma unroll
        for (int it = 0; it < 2; ++it) {
            int oz = ozb + 2 * it;       // 0..3
            float acc = 0.0f;
#pragma unroll
            for (int a = 0; a < 3; ++a) {
                int lz = 2 * oz + a + 1;
#pragma unroll
                for (int b = 0; b < 3; ++b) {
                    int ly = 2 * oy + b + 1;
                    const float* lr = &ls[(lz * LY + ly) * LX + 2 * ox + 3];
                    const float* kr = &kw0[(a * 3 + b) * 3];
                    acc = fmaf(kr[0], lr[0], acc);
                    acc = fmaf(kr[1], lr[1], acc);
                    acc = fmaf(kr[2], lr[2], acc);
                }
            }
            int d = dz * 4 + oz, h = hy * 4 + oy, w = wt * 32 + ox;
            ob1[((size_t)d * S_D1 + h) * S_D1 + w] = acc;
        }
    }

    // ---- 3) d2: 5x5x5 blur stride 4 -> 2x2x16 outputs ----
    // 4 threads per output split the 5 z-planes; shfl-xor reduce within wave.
    {
        float* ob2 = out2 + (size_t)n * D2_PER_BATCH;
        const int q  = tid & 3;
        const int o  = tid >> 2;         // 0..63
        const int ox = o & 15;
        const int oy = (o >> 4) & 1;
        const int oz = o >> 5;
        float acc = 0.0f;
        for (int a = q; a < 5; a += 4) { // q=0 -> planes {0,4}; else {q}
            int lz = 4 * oz + a;
#pragma unroll
            for (int b = 0; b < 5; ++b) {
                int ly = 4 * oy + b;
                const float* lr = &ls[(lz * LY + ly) * LX + 4 * ox + 2];
                const float* kr = &kw1[(a * 5 + b) * 5];
#pragma unroll
                for (int c = 0; c < 5; ++c)
                    acc = fmaf(kr[c], lr[c], acc);
            }
        }
        acc += __shfl_xor(acc, 1);
        acc += __shfl_xor(acc, 2);
        if (q == 0) {
            int d = dz * 2 + oz, h = hy * 2 + oy, w = wt * 16 + ox;
            ob2[((size_t)d * S_D2 + h) * S_D2 + w] = acc;
        }
    }
}

extern "C" void kernel_launch(void* const* d_in, const int* in_sizes, int n_in,
                              void* d_out, int out_size, void* d_ws, size_t ws_size,
                              hipStream_t stream) {
    const float* x  = (const float*)d_in[0];
    const float* k0 = (const float*)d_in[1];   // 27 floats (3x3x3)
    const float* k1 = (const float*)d_in[2];   // 125 floats (5x5x5)

    float* out0 = (float*)d_out;               // x passthrough
    float* out1 = out0 + X_ELEMS;              // d1
    float* out2 = out1 + D1_ELEMS;             // d2

    const int blocks = 4 * 32 * 32 * 2;        // 8192
    fused_pyramid<<<blocks, 256, 0, stream>>>(x, k0, k1, out0, out1, out2);
}

// Round 2
// 303.676 us; speedup vs baseline: 1.1152x; 1.1152x over previous
//
#include <hip/hip_runtime.h>

// Sizes (fixed by the problem)
#define S_IN 256
#define S_D1 128
#define S_D2 64
#define IN_PER_BATCH (S_IN * S_IN * S_IN)
#define D1_PER_BATCH (S_D1 * S_D1 * S_D1)
#define D2_PER_BATCH (S_D2 * S_D2 * S_D2)
#define X_ELEMS (2 * IN_PER_BATCH)
#define D1_ELEMS (2 * D1_PER_BATCH)
#define D2_ELEMS (2 * D2_PER_BATCH)

// Input tile per block: 8x8x32 core, +-2 halo, x staged from x0-4 (16B aligned)
#define TD 8
#define TH 8
#define TW 32
#define LZ 12
#define LY 12
#define LX 40                      // [x0-4, x0+35]
#define NV (LZ * LY * (LX / 4))    // 1440 float4 per tile
#define LDS_ELEMS (LZ * LY * LX)   // 5760 floats = 22.5 KB

__global__ __launch_bounds__(256) void fused_pyramid(
    const float* __restrict__ x, const float* __restrict__ k0,
    const float* __restrict__ k1, float* __restrict__ out0,
    float* __restrict__ out1, float* __restrict__ out2)
{
    __shared__ float ls[LDS_ELEMS];
    __shared__ float kw0[27];
    __shared__ float kw1[125];

    const int tid = threadIdx.x;
    if (tid < 27) kw0[tid] = k0[tid];
    else if (tid >= 32 && tid < 157) kw1[tid - 32] = k1[tid - 32];

    // XCD-contiguous swizzle: 16384 blocks, 8 XCDs, 2048 per XCD (bijective)
    const int bx = blockIdx.x;
    const int lin = (bx & 7) * 2048 + (bx >> 3);
    const int wt = lin & 7;          // 8 x-tiles
    const int hy = (lin >> 3) & 31;  // 32 y-tiles
    const int dz = (lin >> 8) & 31;  // 32 z-tiles
    const int n  = lin >> 13;        // 2 batches

    const int x0 = wt * TW;
    const int y0 = hy * TH;
    const int z0 = dz * TD;

    const float* xb = x + (size_t)n * IN_PER_BATCH;
    float* ob0 = out0 + (size_t)n * IN_PER_BATCH;
    float* ob1 = out1 + (size_t)n * D1_PER_BATCH;
    float* ob2 = out2 + (size_t)n * D2_PER_BATCH;

    // ---- Stage: batch all global loads into regs first ----
    float4 vals[6];
#pragma unroll
    for (int i = 0; i < 6; ++i) {
        int v = tid + (i << 8);
        if (v < NV) {
            int row = v / 10;            // 10 float4 per row
            int j   = v - row * 10;
            int lz  = row / LY;
            int ly  = row - lz * LY;
            int gz = z0 + lz - 2; gz = gz < 0 ? 0 : (gz > 255 ? 255 : gz);
            int gy = y0 + ly - 2; gy = gy < 0 ? 0 : (gy > 255 ? 255 : gy);
            const float* rp = xb + ((size_t)gz * S_IN + gy) * S_IN;
            int gx = x0 - 4 + (j << 2);
            if (gx >= 0 && gx <= S_IN - 4) {
                vals[i] = *reinterpret_cast<const float4*>(rp + gx);
            } else {
                float s = rp[gx < 0 ? 0 : (S_IN - 1)];
                vals[i] = make_float4(s, s, s, s);
            }
        }
    }
    // ---- Write LDS + fused passthrough store of the 8x8x32 core ----
#pragma unroll
    for (int i = 0; i < 6; ++i) {
        int v = tid + (i << 8);
        if (v < NV) {
            int row = v / 10;
            int j   = v - row * 10;
            int lz  = row / LY;
            int ly  = row - lz * LY;
            *reinterpret_cast<float4*>(&ls[(lz * LY + ly) * LX + (j << 2)]) = vals[i];
            if ((unsigned)(lz - 2) < 8u && (unsigned)(ly - 2) < 8u &&
                (unsigned)(j - 1) < 8u) {
                int gz = z0 + lz - 2, gy = y0 + ly - 2, gx = x0 - 4 + (j << 2);
                *reinterpret_cast<float4*>(
                    &ob0[((size_t)gz * S_IN + gy) * S_IN + gx]) = vals[i];
            }
        }
    }
    __syncthreads();

    // ---- d1: 3x3x3 stride-2 -> 4x4x16 outputs, 1 per thread ----
    {
        const int ox = tid & 15;
        const int oy = (tid >> 4) & 3;
        const int oz = tid >> 6;
        float acc = 0.0f;
#pragma unroll
        for (int a = 0; a < 3; ++a) {
            int lz = 2 * oz + 1 + a;
#pragma unroll
            for (int b = 0; b < 3; ++b) {
                int ly = 2 * oy + 1 + b;
                const float* base = &ls[(lz * LY + ly) * LX + 2 * ox + 2];
                float2 v0 = *reinterpret_cast<const float2*>(base);
                float2 v1 = *reinterpret_cast<const float2*>(base + 2);
                const float* kr = &kw0[(a * 3 + b) * 3];
                acc = fmaf(kr[0], v0.y, acc);   // lx = 2ox+3
                acc = fmaf(kr[1], v1.x, acc);   // lx = 2ox+4
                acc = fmaf(kr[2], v1.y, acc);   // lx = 2ox+5
            }
        }
        int d = 4 * dz + oz, h = 4 * hy + oy, w = 16 * wt + ox;
        ob1[((size_t)d * S_D1 + h) * S_D1 + w] = acc;
    }

    // ---- d2: 5x5x5 stride-4 -> 2x2x8 outputs, 8 threads/output ----
    {
        const int q = tid & 7;           // splits the 25 (a,b) rows
        const int o = tid >> 3;          // 0..31
        const int ox = o & 7;
        const int oy = (o >> 3) & 1;
        const int oz = o >> 4;
        float acc = 0.0f;
#pragma unroll
        for (int m = 0; m < 4; ++m) {
            int r = q + (m << 3);
            if (r < 25) {
                int a = r / 5, b = r - 5 * a;
                int lz = 4 * oz + a, ly = 4 * oy + b;
                const float* base = &ls[(lz * LY + ly) * LX + 4 * ox];
                float4 A = *reinterpret_cast<const float4*>(base);
                float4 B = *reinterpret_cast<const float4*>(base + 4);
                const float* kr = &kw1[r * 5];
                acc = fmaf(kr[0], A.z, acc);   // lx = 4ox+2
                acc = fmaf(kr[1], A.w, acc);
                acc = fmaf(kr[2], B.x, acc);
                acc = fmaf(kr[3], B.y, acc);
                acc = fmaf(kr[4], B.z, acc);   // lx = 4ox+6
            }
        }
        acc += __shfl_xor(acc, 1);
        acc += __shfl_xor(acc, 2);
        acc += __shfl_xor(acc, 4);
        if (q == 0) {
            int d = 2 * dz + oz, h = 2 * hy + oy, w = 8 * wt + ox;
            ob2[((size_t)d * S_D2 + h) * S_D2 + w] = acc;
        }
    }
}

extern "C" void kernel_launch(void* const* d_in, const int* in_sizes, int n_in,
                              void* d_out, int out_size, void* d_ws, size_t ws_size,
                              hipStream_t stream) {
    const float* x  = (const float*)d_in[0];
    const float* k0 = (const float*)d_in[1];   // 27 floats (3x3x3)
    const float* k1 = (const float*)d_in[2];   // 125 floats (5x5x5)

    float* out0 = (float*)d_out;               // x passthrough
    float* out1 = out0 + X_ELEMS;              // d1
    float* out2 = out1 + D1_ELEMS;             // d2

    const int blocks = 8 * 32 * 32 * 2;        // 16384
    fused_pyramid<<<blocks, 256, 0, stream>>>(x, k0, k1, out0, out1, out2);
}

// Round 4
// 296.015 us; speedup vs baseline: 1.1440x; 1.0259x over previous
//
#include <hip/hip_runtime.h>

// Sizes (fixed by the problem)
#define S_IN 256
#define IN_PER_BATCH (S_IN * S_IN * S_IN)
#define D1_PER_BATCH (128 * 128 * 128)
#define D2_PER_BATCH (64 * 64 * 64)
#define X_ELEMS (2 * IN_PER_BATCH)
#define D1_ELEMS (2 * D1_PER_BATCH)
#define D2_ELEMS (2 * D2_PER_BATCH)

// Staged tile: 8x8x32 core, +-2 halo (z,y), x staged [x0-4, x0+35]
// Row = 40 floats = 10 float4  -> LDS byte offset of vec v is exactly 16*v
#define LXR 40
#define NROW 144                 // 12 z * 12 y real rows
#define BUFV 1536                // padded to 6 full slots of 256 lanes (>= 1440)
#define BUFF (BUFV * 4)          // 6144 floats per buffer
#define TPB 8                    // tiles per block
#define NBLK 2048

__device__ __forceinline__ void gload_lds16(const float* g, float* l) {
    __builtin_amdgcn_global_load_lds(
        (const __attribute__((address_space(1))) void*)g,
        (__attribute__((address_space(3))) void*)l, 16, 0, 0);
}

__global__ __launch_bounds__(256) void fused_pyramid(
    const float* __restrict__ x, const float* __restrict__ k0,
    const float* __restrict__ k1, float* __restrict__ out0,
    float* __restrict__ out1, float* __restrict__ out2)
{
    __shared__ float ls[2 * BUFF];
    __shared__ float kw0[9][4];      // 3x3x3 weights, rows padded to 4
    __shared__ float kw1[25][8];     // 5x5x5 weights, rows padded to 8

    const int tid = threadIdx.x;
    if (tid < 27) kw0[tid / 3][tid % 3] = k0[tid];
    else if (tid >= 32 && tid < 157) {
        int t = tid - 32;
        kw1[t / 5][t % 5] = k1[t];
    }

    const int bid  = blockIdx.x;
    const int wt   = bid & 7;            // x-tile (fixed per block)
    const int hy   = (bid >> 3) & 31;    // y-tile (fixed per block)
    const int dzn0 = bid >> 8;           // 0..7; tile t has dzn = dzn0 + 8*t
    const int x0 = wt << 5;
    const int y0 = hy << 3;
    const bool edge = (wt == 0);         // block-uniform

    // ---- per-slot DMA constants (v = tid + 256*i, LDS byte = 16*v) ----
    int gcol[6];    // clamped gy*256 + clamped gx  (gx clamped to [0,252])
    int lzo[6];     // lz - 2
#pragma unroll
    for (int i = 0; i < 6; ++i) {
        int v = tid + (i << 8);
        int row = v / 10;                // 10 float4 per LDS row
        int j = v - row * 10;
        int lz = row / 12;               // pad slots give lz >= 12 (harmless)
        int ly = row - lz * 12;
        int gy = y0 + ly - 2; gy = gy < 0 ? 0 : (gy > 255 ? 255 : gy);
        int gx = x0 - 4 + (j << 2); gx = gx < 0 ? 0 : (gx > 252 ? 252 : gx);
        gcol[i] = (gy << 8) + gx;
        lzo[i] = lz - 2;
    }

    // ---- left-edge patch constants (only wt==0 blocks use them) ----
    const bool pact = edge && (tid < NROW);
    int plz = 0, ply = 0, pgy = 0;
    if (pact) {
        plz = tid / 12;
        ply = tid - plz * 12;
        int gy = y0 + ply - 2; pgy = gy < 0 ? 0 : (gy > 255 ? 255 : gy);
    }
    float pv = 0.0f;

    auto issue_dma = [&](int dzn, int buf) {
        const int z0 = (dzn & 31) << 3;
        const float* xb = x + (size_t)(dzn >> 5) * IN_PER_BATCH;
        float* lb = ls + buf * BUFF + (tid << 2);   // per-lane: base + lane*16B
#pragma unroll
        for (int i = 0; i < 6; ++i) {
            int gz = z0 + lzo[i]; gz = gz < 0 ? 0 : (gz > 255 ? 255 : gz);
            gload_lds16(xb + (((size_t)gz << 16) + gcol[i]), lb + (size_t)i * 1024);
        }
    };
    auto patch_load = [&](int dzn) {
        if (pact) {
            int z0 = (dzn & 31) << 3;
            int gz = z0 + plz - 2; gz = gz < 0 ? 0 : (gz > 255 ? 255 : gz);
            pv = x[(size_t)(dzn >> 5) * IN_PER_BATCH + ((size_t)gz << 16) + (pgy << 8)];
        }
    };
    auto patch_write = [&](int buf) {
        if (pact) {
            // columns c2,c3 correspond to gx=-2,-1 -> replicate x[...,0]
            *reinterpret_cast<float2*>(
                &ls[buf * BUFF + (plz * 12 + ply) * LXR + 2]) = make_float2(pv, pv);
        }
    };

    auto compute = [&](int dzn, int buf) {
        const int dz = dzn & 31;
        const int n  = dzn >> 5;
        const float* B = ls + buf * BUFF;

        // 1) passthrough copy of the 8x8x32 core (LDS -> global, float4)
        {
            float* ob0 = out0 + (size_t)n * IN_PER_BATCH
                       + (((size_t)dz << 3) << 16) + (y0 << 8) + x0;
#pragma unroll
            for (int k = 0; k < 2; ++k) {
                int v = tid + (k << 8);      // 0..511 core float4s
                int jj = v & 7;
                int rowc = v >> 3;           // 0..63 (8z x 8y)
                int lzc = rowc >> 3, lyc = rowc & 7;
                float4 val = *reinterpret_cast<const float4*>(
                    &B[((lzc + 2) * 12 + (lyc + 2)) * LXR + 4 + (jj << 2)]);
                *reinterpret_cast<float4*>(
                    &ob0[((size_t)lzc << 16) + (lyc << 8) + (jj << 2)]) = val;
            }
        }

        // 2) d1: 3x3x3 stride-2 -> 4x4x16 outputs, 1 per thread
        {
            const int ox = tid & 15, oy = (tid >> 4) & 3, oz = tid >> 6;
            const float* base = B + ((2 * oz + 1) * 12 + (2 * oy + 1)) * LXR + 2 * ox + 2;
            float acc = 0.0f;
#pragma unroll
            for (int a = 0; a < 3; ++a)
#pragma unroll
                for (int b = 0; b < 3; ++b) {
                    const float* lr = base + (a * 12 + b) * LXR;
                    float2 v0 = *reinterpret_cast<const float2*>(lr);
                    float2 v1 = *reinterpret_cast<const float2*>(lr + 2);
                    float4 kr = *reinterpret_cast<const float4*>(&kw0[a * 3 + b][0]);
                    acc = fmaf(kr.x, v0.y, acc);
                    acc = fmaf(kr.y, v1.x, acc);
                    acc = fmaf(kr.z, v1.y, acc);
                }
            float* ob1 = out1 + (size_t)n * D1_PER_BATCH
                       + (((size_t)dz << 2) << 14) + ((hy << 2) << 7) + (wt << 4);
            ob1[(oz << 14) + (oy << 7) + ox] = acc;
        }

        // 3) d2: 5x5x5 stride-4 -> 2x2x8 outputs, 8 threads/output
        {
            const int q = tid & 7;
            const int o = tid >> 3;
            const int ox = o & 7, oy = (o >> 3) & 1, oz = o >> 4;
            float acc = 0.0f;
#pragma unroll
            for (int m = 0; m < 4; ++m) {
                int r = q + (m << 3);
                if (r < 25) {
                    int a = r / 5, b = r - 5 * a;
                    const float* lr = B + ((4 * oz + a) * 12 + (4 * oy + b)) * LXR + 4 * ox;
                    float4 A4 = *reinterpret_cast<const float4*>(lr);
                    float4 B4 = *reinterpret_cast<const float4*>(lr + 4);
                    float4 kr = *reinterpret_cast<const float4*>(&kw1[r][0]);
                    float k4 = kw1[r][4];
                    acc = fmaf(kr.x, A4.z, acc);
                    acc = fmaf(kr.y, A4.w, acc);
                    acc = fmaf(kr.z, B4.x, acc);
                    acc = fmaf(kr.w, B4.y, acc);
                    acc = fmaf(k4,   B4.z, acc);
                }
            }
            acc += __shfl_xor(acc, 1);
            acc += __shfl_xor(acc, 2);
            acc += __shfl_xor(acc, 4);
            if (q == 0) {
                float* ob2 = out2 + (size_t)n * D2_PER_BATCH
                           + (((size_t)dz << 1) << 12) + ((hy << 1) << 6) + (wt << 3);
                ob2[(oz << 12) + (oy << 6) + ox] = acc;
            }
        }
    };

    // ---- pipelined main loop: DMA(t+1) overlaps compute(t) ----
    issue_dma(dzn0, 0);
    if (edge) patch_load(dzn0);
    __syncthreads();                       // drains DMA (vmcnt 0) -> buf0 ready
    if (edge) { patch_write(0); __syncthreads(); }

    for (int it = 0; it < TPB; ++it) {
        const int cur = it & 1;
        if (it + 1 < TPB) {
            issue_dma(dzn0 + 8 * (it + 1), cur ^ 1);
            if (edge) patch_load(dzn0 + 8 * (it + 1));
        }
        compute(dzn0 + 8 * it, cur);
        __syncthreads();                   // prev reads done + next DMA landed
        if (edge && it + 1 < TPB) { patch_write(cur ^ 1); __syncthreads(); }
    }
}

extern "C" void kernel_launch(void* const* d_in, const int* in_sizes, int n_in,
                              void* d_out, int out_size, void* d_ws, size_t ws_size,
                              hipStream_t stream) {
    const float* x  = (const float*)d_in[0];
    const float* k0 = (const float*)d_in[1];   // 27 floats (3x3x3)
    const float* k1 = (const float*)d_in[2];   // 125 floats (5x5x5)

    float* out0 = (float*)d_out;               // x passthrough
    float* out1 = out0 + X_ELEMS;              // d1
    float* out2 = out1 + D1_ELEMS;             // d2

    fused_pyramid<<<NBLK, 256, 0, stream>>>(x, k0, k1, out0, out1, out2);
}

// Round 5
// 294.411 us; speedup vs baseline: 1.1502x; 1.0054x over previous
//
#include <hip/hip_runtime.h>

// Sizes (fixed by the problem)
#define S_IN 256
#define IN_PER_BATCH (S_IN * S_IN * S_IN)
#define D1_PER_BATCH (128 * 128 * 128)
#define D2_PER_BATCH (64 * 64 * 64)
#define X_ELEMS (2 * IN_PER_BATCH)
#define D1_ELEMS (2 * D1_PER_BATCH)
#define D2_ELEMS (2 * D2_PER_BATCH)

// Staged tile: 8x8x32 core, +-2 halo (z,y), x staged [x0-4, x0+35]
// Row = 40 floats = 10 float4  -> LDS byte offset of vec v is exactly 16*v
#define LXR 40
#define NROW 144                 // 12 z * 12 y real rows
#define BUFV 1536                // padded to 6 full slots of 256 lanes (>= 1440)
#define BUFF (BUFV * 4)          // 6144 floats = 24 KB
#define NBLK 16384

__device__ __forceinline__ void gload_lds16(const float* g, float* l) {
    __builtin_amdgcn_global_load_lds(
        (const __attribute__((address_space(1))) void*)g,
        (__attribute__((address_space(3))) void*)l, 16, 0, 0);
}

__global__ __launch_bounds__(256, 6) void fused_pyramid(
    const float* __restrict__ x, const float* __restrict__ k0,
    const float* __restrict__ k1, float* __restrict__ out0,
    float* __restrict__ out1, float* __restrict__ out2)
{
    __shared__ float ls[BUFF];
    __shared__ float kw0[9][4];      // 3x3x3 weights, rows padded to 4
    __shared__ float kw1[25][8];     // 5x5x5 weights, rows padded to 8

    const int tid = threadIdx.x;
    if (tid < 27) kw0[tid / 3][tid % 3] = k0[tid];
    else if (tid >= 32 && tid < 157) {
        int t = tid - 32;
        kw1[t / 5][t % 5] = k1[t];
    }

    // XCD-contiguous swizzle: 16384 = 8 * 2048 (bijective). Same-XCD blocks
    // are spatial neighbors -> halo re-reads hit that XCD's L2.
    const int bx  = blockIdx.x;
    const int lin = (bx & 7) * 2048 + (bx >> 3);
    const int wt = lin & 7;           // 8 x-tiles
    const int hy = (lin >> 3) & 31;   // 32 y-tiles
    const int dz = (lin >> 8) & 31;   // 32 z-tiles
    const int n  = lin >> 13;         // 2 batches

    const int x0 = wt << 5;
    const int y0 = hy << 3;
    const int z0 = dz << 3;
    const bool edge = (wt == 0);      // block-uniform

    const float* xb = x + (size_t)n * IN_PER_BATCH;

    // ---- issue all staging DMA (wave-uniform LDS base + lane*16) ----
    {
        float* lb = ls + (tid << 2);
#pragma unroll
        for (int i = 0; i < 6; ++i) {
            int v = tid + (i << 8);
            int row = v / 10;            // 10 float4 per LDS row
            int j = v - row * 10;
            int lz = row / 12;           // pad slots give lz up to 12 (clamped)
            int ly = row - lz * 12;
            int gz = z0 + lz - 2; gz = gz < 0 ? 0 : (gz > 255 ? 255 : gz);
            int gy = y0 + ly - 2; gy = gy < 0 ? 0 : (gy > 255 ? 255 : gy);
            int gx = x0 - 4 + (j << 2); gx = gx < 0 ? 0 : (gx > 252 ? 252 : gx);
            gload_lds16(xb + (((size_t)gz << 16) + (gy << 8) + gx),
                        lb + (size_t)i * 1024);
        }
    }

    // ---- left-edge patch value (wt==0 only): columns gx=-2,-1 -> x[...,0]
    float pv = 0.0f;
    int plz = 0, ply = 0;
    const bool pact = edge && (tid < NROW);
    if (pact) {
        plz = tid / 12;
        ply = tid - plz * 12;
        int gz = z0 + plz - 2; gz = gz < 0 ? 0 : (gz > 255 ? 255 : gz);
        int gy = y0 + ply - 2; gy = gy < 0 ? 0 : (gy > 255 ? 255 : gy);
        pv = xb[((size_t)gz << 16) + (gy << 8)];
    }

    __syncthreads();                   // drains vmcnt -> DMA landed
    if (edge) {
        if (pact)
            *reinterpret_cast<float2*>(
                &ls[(plz * 12 + ply) * LXR + 2]) = make_float2(pv, pv);
        __syncthreads();
    }

    // ---- 1) passthrough copy of the 8x8x32 core (LDS -> global, float4) ----
    {
        float* ob0 = out0 + (size_t)n * IN_PER_BATCH
                   + (((size_t)dz << 3) << 16) + (y0 << 8) + x0;
#pragma unroll
        for (int k = 0; k < 2; ++k) {
            int v = tid + (k << 8);      // 0..511 core float4s
            int jj = v & 7;
            int rowc = v >> 3;           // 0..63 (8z x 8y)
            int lzc = rowc >> 3, lyc = rowc & 7;
            float4 val = *reinterpret_cast<const float4*>(
                &ls[((lzc + 2) * 12 + (lyc + 2)) * LXR + 4 + (jj << 2)]);
            *reinterpret_cast<float4*>(
                &ob0[((size_t)lzc << 16) + (lyc << 8) + (jj << 2)]) = val;
        }
    }

    // ---- 2) d1: 3x3x3 stride-2 -> 4x4x16 outputs, 1 per thread ----
    {
        const int ox = tid & 15, oy = (tid >> 4) & 3, oz = tid >> 6;
        const float* base = ls + ((2 * oz + 1) * 12 + (2 * oy + 1)) * LXR + 2 * ox + 2;
        float acc = 0.0f;
#pragma unroll
        for (int a = 0; a < 3; ++a)
#pragma unroll
            for (int b = 0; b < 3; ++b) {
                const float* lr = base + (a * 12 + b) * LXR;
                float2 v0 = *reinterpret_cast<const float2*>(lr);
                float2 v1 = *reinterpret_cast<const float2*>(lr + 2);
                float4 kr = *reinterpret_cast<const float4*>(&kw0[a * 3 + b][0]);
                acc = fmaf(kr.x, v0.y, acc);
                acc = fmaf(kr.y, v1.x, acc);
                acc = fmaf(kr.z, v1.y, acc);
            }
        float* ob1 = out1 + (size_t)n * D1_PER_BATCH
                   + (((size_t)dz << 2) << 14) + ((hy << 2) << 7) + (wt << 4);
        ob1[(oz << 14) + (oy << 7) + ox] = acc;
    }

    // ---- 3) d2: 5x5x5 stride-4 -> 2x2x8 outputs, 8 threads/output ----
    {
        const int q = tid & 7;
        const int o = tid >> 3;
        const int ox = o & 7, oy = (o >> 3) & 1, oz = o >> 4;
        float acc = 0.0f;
#pragma unroll
        for (int m = 0; m < 4; ++m) {
            int r = q + (m << 3);
            if (r < 25) {
                int a = r / 5, b = r - 5 * a;
                const float* lr = ls + ((4 * oz + a) * 12 + (4 * oy + b)) * LXR + 4 * ox;
                float4 A4 = *reinterpret_cast<const float4*>(lr);
                float4 B4 = *reinterpret_cast<const float4*>(lr + 4);
                float4 kr = *reinterpret_cast<const float4*>(&kw1[r][0]);
                float k4 = kw1[r][4];
                acc = fmaf(kr.x, A4.z, acc);
                acc = fmaf(kr.y, A4.w, acc);
                acc = fmaf(kr.z, B4.x, acc);
                acc = fmaf(kr.w, B4.y, acc);
                acc = fmaf(k4,   B4.z, acc);
            }
        }
        acc += __shfl_xor(acc, 1);
        acc += __shfl_xor(acc, 2);
        acc += __shfl_xor(acc, 4);
        if (q == 0) {
            float* ob2 = out2 + (size_t)n * D2_PER_BATCH
                       + (((size_t)dz << 1) << 12) + ((hy << 1) << 6) + (wt << 3);
            ob2[(oz << 12) + (oy << 6) + ox] = acc;
        }
    }
}

extern "C" void kernel_launch(void* const* d_in, const int* in_sizes, int n_in,
                              void* d_out, int out_size, void* d_ws, size_t ws_size,
                              hipStream_t stream) {
    const float* x  = (const float*)d_in[0];
    const float* k0 = (const float*)d_in[1];   // 27 floats (3x3x3)
    const float* k1 = (const float*)d_in[2];   // 125 floats (5x5x5)

    float* out0 = (float*)d_out;               // x passthrough
    float* out1 = out0 + X_ELEMS;              // d1
    float* out2 = out1 + D1_ELEMS;             // d2

    fused_pyramid<<<NBLK, 256, 0, stream>>>(x, k0, k1, out0, out1, out2);
}